// Round 16
// baseline (238.357 us; speedup 1.0000x reference)
//
#include <hip/hip_runtime.h>
#include <cfloat>
#include <stdint.h>

#define B_ 16
#define N_ 4096
#define M_ 1024
#define EPS_ 1e-12f

typedef float v2f __attribute__((ext_vector_type(2)));

__device__ __forceinline__ v2f fma2(v2f a, v2f b, v2f c) {
    return __builtin_elementwise_fma(a, b, c);     // -> v_pk_fma_f32
}
__device__ __forceinline__ v2f splat(float x) { return (v2f){x, x}; }

__device__ __forceinline__ uint32_t umin3(uint32_t a, uint32_t b, uint32_t c) {
    return min(a, min(b, c));                      // -> v_min3_u32
}
__device__ __forceinline__ uint32_t umed3(uint32_t a, uint32_t b, uint32_t c) {
    return max(min(a, b), min(max(a, b), c));      // -> v_med3_u32
}

// R14 hot loops and tiling, but 16 KB LDS/block -> 6 blocks/CU (24 waves/CU):
// role-1 stages the same 4096 pts in 4 phases of 1024 (same total staging
// instructions as R14's 2x2048 — only +4 barriers), role-0 already fits.
// This is the occupancy push of R6/R12 WITHOUT the tile-shrink staging
// duplication that sank those rounds.
// 768 blocks. AoS-PAIR LDS: A[k]=(x2k,x2k+1,y2k,y2k+1), B[k]=(z.., w..);
// each j-iter = 2 ds_read_b128 with 16-bit imm offsets, zero addr VALU.
// blocks [0,256):  cd1, 256 pts each; sA=tid&15 owns pair k=j*16+sA,
//   gA=tid>>4 owns 16 pts. A doubled coords, B=(2z..,|s|^2..); per pt per
//   pair: 3 pk_fma + v_min3_f32 (|p|^2 added post-min; monotone).
// blocks [256,768): knn (cd2+normal), 32 m each; s=tid&31 owns pair
//   k=j*32+s (j<16/phase), g=tid>>5 owns 4 chains. B.w = |q|^2 + C_block at
//   staging (C_block = block-max |m|^2, uniform across merge lanes and per
//   chain -> ordering preserved, t >= 0 so uint key order == float order).
//   Packed key = (bits(t)&~0xFFF)|n (low 12 bits break ties toward smaller
//   n like top_k). Exact distance recomputed for winners in the epilogue.
__global__ __launch_bounds__(256, 6) void fused_kernel(const float* __restrict__ shape_xyz,
                                                       const float* __restrict__ skel_xyz,
                                                       const float* __restrict__ skel_nori,
                                                       float* __restrict__ out)
{
    __shared__ float ls[4096];     // 16 KB: A = ls[0..2047], B = ls[2048..4095]
    __shared__ float ws[4];

    const int tid = threadIdx.x;
    float4* A4 = (float4*)ls;                  // 512 pair-quads
    float4* Bq = (float4*)(ls + 2048);
    float v = 0.0f;

    if (blockIdx.x < 256) {
        // ================= role 0: cd1 =================
        const int b    = blockIdx.x >> 4;      // 16 tiles per b
        const int tile = blockIdx.x & 15;

        // skel staging: thread t loads float4 3t..3t+2 = pts 4t..4t+3 = pairs 2t,2t+1
        const float4* g4 = (const float4*)(skel_xyz + (size_t)b * M_ * 3);
        const float4 r0 = g4[3 * tid + 0];
        const float4 r1 = g4[3 * tid + 1];
        const float4 r2 = g4[3 * tid + 2];

        const int sA = tid & 15;
        const int gA = tid >> 4;
        const int n0 = tile * 256 + gA * 16;
        const float* p = shape_xyz + ((size_t)b * N_ + n0) * 6;
        float nx[16], ny[16], nz[16], best[16];
#pragma unroll
        for (int k = 0; k < 16; ++k) {
            nx[k] = -p[k * 6 + 0];
            ny[k] = -p[k * 6 + 1];
            nz[k] = -p[k * 6 + 2];
            best[k] = FLT_MAX;
        }

        {
            // pts: p0=(r0.x,r0.y,r0.z) p1=(r0.w,r1.x,r1.y) p2=(r1.z,r1.w,r2.x) p3=(r2.y,r2.z,r2.w)
            const float w0 = fmaf(r0.x, r0.x, fmaf(r0.y, r0.y, r0.z * r0.z));
            const float w1 = fmaf(r0.w, r0.w, fmaf(r1.x, r1.x, r1.y * r1.y));
            const float w2 = fmaf(r1.z, r1.z, fmaf(r1.w, r1.w, r2.x * r2.x));
            const float w3 = fmaf(r2.y, r2.y, fmaf(r2.z, r2.z, r2.w * r2.w));
            A4[2 * tid + 0] = make_float4(2*r0.x, 2*r0.w, 2*r0.y, 2*r1.x);
            Bq[2 * tid + 0] = make_float4(2*r0.z, 2*r1.y, w0, w1);
            A4[2 * tid + 1] = make_float4(2*r1.z, 2*r2.y, 2*r1.w, 2*r2.z);
            Bq[2 * tid + 1] = make_float4(2*r2.x, 2*r2.w, w2, w3);
        }
        __syncthreads();

#pragma unroll 4
        for (int j = 0; j < 32; ++j) {             // pair (2k, 2k+1), k = j*16+sA
            const float4 a = A4[j * 16 + sA];      // -> ds_read_b128, imm offset
            const float4 bq = Bq[j * 16 + sA];
            const v2f sx = {a.x, a.y};
            const v2f sy = {a.z, a.w};
            const v2f sz = {bq.x, bq.y};
            const v2f sw = {bq.z, bq.w};
#pragma unroll
            for (int k = 0; k < 16; ++k) {
                const v2f t = fma2(splat(nx[k]), sx,
                              fma2(splat(ny[k]), sy,
                              fma2(splat(nz[k]), sz, sw)));
                best[k] = fminf(best[k], fminf(t.x, t.y));   // -> v_min3_f32
            }
        }

#pragma unroll
        for (int off = 1; off < 16; off <<= 1) {
#pragma unroll
            for (int k = 0; k < 16; ++k) best[k] = fminf(best[k], __shfl_xor(best[k], off));
        }
        if (sA == 0) {
#pragma unroll
            for (int k = 0; k < 16; ++k) {
                const float pp = fmaf(nx[k], nx[k], fmaf(ny[k], ny[k], nz[k] * nz[k]));
                v += sqrtf(fmaxf(best[k] + pp, EPS_));
            }
            v *= 1e-4f;
        }
    } else {
        // ================= role 1: knn (cd2 + normal loss) =================
        const int id  = blockIdx.x - 256;
        const int b   = id >> 5;                   // 32 blocks per b
        const int sub = id & 31;
        const int s   = tid & 31;
        const int g   = tid >> 5;                  // 0..7
        const int m0  = sub * 32 + g * 4;          // 4 chains per lane

        float m2x[4], m2y[4], m2z[4], aa[4];
        uint32_t k1[4], k2[4];
        {
            const float* sq = skel_xyz + ((size_t)b * M_ + m0) * 3;
#pragma unroll
            for (int c = 0; c < 4; ++c) {
                const float x = sq[c * 3 + 0];
                const float y = sq[c * 3 + 1];
                const float z = sq[c * 3 + 2];
                m2x[c] = -2.0f * x; m2y[c] = -2.0f * y; m2z[c] = -2.0f * z;
                aa[c]  = fmaf(x, x, fmaf(y, y, z * z));
                k1[c] = 0xFFFFFFFFu; k2[c] = 0xFFFFFFFFu;
            }
        }
        // block-max of aa -> C (uniform across merge lanes; per chain the key
        // value is d^2 + (C - aa_c), a constant shift -> ordering preserved)
        float amax = fmaxf(fmaxf(aa[0], aa[1]), fmaxf(aa[2], aa[3]));
#pragma unroll
        for (int off = 1; off < 64; off <<= 1) amax = fmaxf(amax, __shfl_xor(amax, off));
        if ((tid & 63) == 0) ws[tid >> 6] = amax;

        const uint32_t HI = 0xFFFFF000u;
        const float* sb = shape_xyz + (size_t)b * N_ * 6;
        const float4* g4 = (const float4*)sb;

        // prefetch phase 0: thread t holds float4 6t..6t+5 = pts 4t..4t+3
        float4 r[6];
#pragma unroll
        for (int k = 0; k < 6; ++k) r[k] = g4[6 * tid + k];

        float C = 0.0f;
        for (int ph = 0; ph < 4; ++ph) {           // 4 phases x 1024 pts (16 KB)
            __syncthreads();   // ph0: ws visible; ph>0: previous ls reads done
            if (ph == 0) C = fmaxf(fmaxf(ws[0], ws[1]), fmaxf(ws[2], ws[3]));
            {
                // pts 4t..4t+3 = pairs 2t, 2t+1 of this phase
                const float4 a0 = r[0], a1 = r[1], a2 = r[2];
                const float4 a3 = r[3], a4 = r[4], a5 = r[5];
                // q0=(a0.x,a0.y,a0.z) q1=(a1.z,a1.w,a2.x) q2=(a3.x,a3.y,a3.z) q3=(a4.z,a4.w,a5.x)
                const float w0 = fmaf(a0.x, a0.x, fmaf(a0.y, a0.y, a0.z * a0.z)) + C;
                const float w1 = fmaf(a1.z, a1.z, fmaf(a1.w, a1.w, a2.x * a2.x)) + C;
                const float w2 = fmaf(a3.x, a3.x, fmaf(a3.y, a3.y, a3.z * a3.z)) + C;
                const float w3 = fmaf(a4.z, a4.z, fmaf(a4.w, a4.w, a5.x * a5.x)) + C;
                A4[2 * tid + 0] = make_float4(a0.x, a1.z, a0.y, a1.w);
                Bq[2 * tid + 0] = make_float4(a0.z, a2.x, w0, w1);
                A4[2 * tid + 1] = make_float4(a3.x, a4.z, a3.y, a4.w);
                Bq[2 * tid + 1] = make_float4(a3.z, a5.x, w2, w3);
            }
            __syncthreads();
            // issue next phase's loads now; j-loop below hides their latency.
            // phase stride = 1024 pts * 6 floats / 4 = 1536 float4.
            if (ph < 3) {
                const int base = (ph + 1) * 1536 + 6 * tid;
#pragma unroll
                for (int k = 0; k < 6; ++k) r[k] = g4[base + k];
            }
            const uint32_t nb = (uint32_t)(ph * 1024);

#pragma unroll 8
            for (int j = 0; j < 16; ++j) {         // pair (2k, 2k+1), k = j*32+s
                const float4 a = A4[j * 32 + s];   // -> ds_read_b128, imm offset
                const float4 bq = Bq[j * 32 + s];
                const v2f qx = {a.x, a.y};
                const v2f qy = {a.z, a.w};
                const v2f qz = {bq.x, bq.y};
                const v2f qw = {bq.z, bq.w};
                const uint32_t gn0 = nb + (uint32_t)(j * 64 + 2 * s);
                const uint32_t gn1 = gn0 + 1u;
#pragma unroll
                for (int c = 0; c < 4; ++c) {
                    const v2f t = fma2(splat(m2x[c]), qx,
                                  fma2(splat(m2y[c]), qy,
                                  fma2(splat(m2z[c]), qz, qw)));
                    const uint32_t kk0 = (__float_as_uint(t.x) & HI) | gn0;
                    const uint32_t kk1 = (__float_as_uint(t.y) & HI) | gn1;
                    k2[c] = min(k2[c], umed3(k1[c], kk0, kk1));
                    k1[c] = umin3(k1[c], kk0, kk1);
                }
            }
        }

        // butterfly top-2 merge across the 32 s-lanes
#pragma unroll
        for (int off = 1; off < 32; off <<= 1) {
#pragma unroll
            for (int c = 0; c < 4; ++c) {
                const uint32_t o1 = (uint32_t)__shfl_xor((int)k1[c], off);
                const uint32_t o2 = (uint32_t)__shfl_xor((int)k2[c], off);
                const uint32_t nk2 = min(min(k2[c], o2), max(k1[c], o1));
                k1[c] = min(k1[c], o1);
                k2[c] = nk2;
            }
        }

        if (s == 0) {
            const float* no = skel_nori + ((size_t)b * M_ + m0) * 3;
            const float kN = 0.001f * 0.5f / (float)B_;
#pragma unroll
            for (int c = 0; c < 4; ++c) {
                const int i1 = (int)(k1[c] & 0xFFFu);
                const int i2 = (int)(k2[c] & 0xFFFu);
                const float* p1 = sb + (size_t)i1 * 6;
                const float* p2 = sb + (size_t)i2 * 6;
                // exact nearest distance (removes key quantization from cd2)
                const float ax = -0.5f * m2x[c], ay = -0.5f * m2y[c], az = -0.5f * m2z[c];
                const float dx = ax - p1[0], dy = ay - p1[1], dz = az - p1[2];
                const float d2 = fmaf(dx, dx, fmaf(dy, dy, dz * dz));
                const float q0 = no[c * 3 + 0], q1 = no[c * 3 + 1], q2 = no[c * 3 + 2];
                const float dot1 = q0 * p1[3] + q1 * p1[4] + q2 * p1[5];
                const float dot2 = q0 * p2[3] + q1 * p2[4] + q2 * p2[5];
                v += sqrtf(fmaxf(d2, EPS_)) * 1e-4f + (fabsf(dot1) + fabsf(dot2)) * kN;
            }
        }
    }

    // block reduction + one atomic per block
#pragma unroll
    for (int off = 32; off > 0; off >>= 1) v += __shfl_down(v, off);
    __syncthreads();                     // ws safely reusable (role 1 read it in ph0)
    if ((tid & 63) == 0) ws[tid >> 6] = v;
    __syncthreads();
    if (tid == 0) atomicAdd(out, ws[0] + ws[1] + ws[2] + ws[3]);
}

extern "C" void kernel_launch(void* const* d_in, const int* in_sizes, int n_in,
                              void* d_out, int out_size, void* d_ws, size_t ws_size,
                              hipStream_t stream) {
    const float* shape_xyz = (const float*)d_in[0];  // (16, 4096, 6)
    const float* skel_xyz  = (const float*)d_in[1];  // (16, 1024, 3)
    const float* skel_nori = (const float*)d_in[2];  // (16, 1024, 3)
    float* out = (float*)d_out;                      // scalar

    hipMemsetAsync(out, 0, sizeof(float), stream);   // d_out poisoned each call
    fused_kernel<<<768, 256, 0, stream>>>(shape_xyz, skel_xyz, skel_nori, out);
}

// Round 17
// 112.509 us; speedup vs baseline: 2.1186x; 2.1186x over previous
//
#include <hip/hip_runtime.h>
#include <cfloat>
#include <stdint.h>

#define B_ 16
#define N_ 4096
#define M_ 1024
#define EPS_ 1e-12f

typedef float v2f __attribute__((ext_vector_type(2)));

__device__ __forceinline__ v2f fma2(v2f a, v2f b, v2f c) {
    return __builtin_elementwise_fma(a, b, c);     // -> v_pk_fma_f32
}
__device__ __forceinline__ v2f splat(float x) { return (v2f){x, x}; }

__device__ __forceinline__ uint32_t umin3(uint32_t a, uint32_t b, uint32_t c) {
    return min(a, min(b, c));                      // -> v_min3_u32
}
__device__ __forceinline__ uint32_t umed3(uint32_t a, uint32_t b, uint32_t c) {
    return max(min(a, b), min(max(a, b), c));      // -> v_med3_u32
}

// R14 structure with LDS trimmed to EXACTLY 32768 B -> 5 blocks/CU (R14's
// ws[4] pushed the block to 33280 B -> only 4/CU). ws eliminated by:
//   (a) final reduction = per-wave shfl reduce + one atomicAdd per wave;
//   (b) role-1 positivity constant C is WAVE-local (the top-2 merge never
//       crosses the wave, so C only needs wave uniformity); staged w is
//       plain |q|^2 and the hot loop adds splat(C) once per iter (shared
//       across 4 chains). Keep __launch_bounds__(256,3): the allocator is
//       untouched (R16 showed capping it causes scratch spills).
// 768 blocks. AoS-PAIR LDS: A[k]=(x2k,x2k+1,y2k,y2k+1), B[k]=(z..,w..);
// each j-iter = 2 ds_read_b128 with 16-bit imm offsets, zero addr VALU.
// blocks [0,256):  cd1, 256 pts each; sA=tid&15 owns pair k=j*16+sA,
//   gA=tid>>4 owns 16 pts. A doubled coords, B=(2z..,|s|^2..); per pt per
//   pair: 3 pk_fma + v_min3_f32 (|p|^2 added post-min; monotone).
// blocks [256,768): knn (cd2+normal), 32 m each; s=tid&31 owns pair
//   k=j*32+s, g=tid>>5 owns 4 chains. 2 staging phases of 2048 pts.
//   Key t = d^2 + (C - aa_c) >= 0 (C = wave-max |m|^2 * 1.03125, constant
//   per chain -> ordering preserved; t >= 0 so uint key order == float
//   order). Packed key = (bits(t)&~0xFFF)|n (low 12 bits break ties toward
//   smaller n like top_k). Exact distance recomputed for winners.
__global__ __launch_bounds__(256, 3) void fused_kernel(const float* __restrict__ shape_xyz,
                                                       const float* __restrict__ skel_xyz,
                                                       const float* __restrict__ skel_nori,
                                                       float* __restrict__ out)
{
    __shared__ float ls[8192];     // exactly 32 KB: A = ls[0..4095], B = ls[4096..8191]

    const int tid = threadIdx.x;
    float4* A4 = (float4*)ls;
    float4* Bq = (float4*)(ls + 4096);
    float v = 0.0f;

    if (blockIdx.x < 256) {
        // ================= role 0: cd1 =================
        const int b    = blockIdx.x >> 4;      // 16 tiles per b
        const int tile = blockIdx.x & 15;

        // skel staging: thread t loads float4 3t..3t+2 = pts 4t..4t+3 = pairs 2t,2t+1
        const float4* g4 = (const float4*)(skel_xyz + (size_t)b * M_ * 3);
        const float4 r0 = g4[3 * tid + 0];
        const float4 r1 = g4[3 * tid + 1];
        const float4 r2 = g4[3 * tid + 2];

        const int sA = tid & 15;
        const int gA = tid >> 4;
        const int n0 = tile * 256 + gA * 16;
        const float* p = shape_xyz + ((size_t)b * N_ + n0) * 6;
        float nx[16], ny[16], nz[16], best[16];
#pragma unroll
        for (int k = 0; k < 16; ++k) {
            nx[k] = -p[k * 6 + 0];
            ny[k] = -p[k * 6 + 1];
            nz[k] = -p[k * 6 + 2];
            best[k] = FLT_MAX;
        }

        {
            // pts: p0=(r0.x,r0.y,r0.z) p1=(r0.w,r1.x,r1.y) p2=(r1.z,r1.w,r2.x) p3=(r2.y,r2.z,r2.w)
            const float w0 = fmaf(r0.x, r0.x, fmaf(r0.y, r0.y, r0.z * r0.z));
            const float w1 = fmaf(r0.w, r0.w, fmaf(r1.x, r1.x, r1.y * r1.y));
            const float w2 = fmaf(r1.z, r1.z, fmaf(r1.w, r1.w, r2.x * r2.x));
            const float w3 = fmaf(r2.y, r2.y, fmaf(r2.z, r2.z, r2.w * r2.w));
            A4[2 * tid + 0] = make_float4(2*r0.x, 2*r0.w, 2*r0.y, 2*r1.x);
            Bq[2 * tid + 0] = make_float4(2*r0.z, 2*r1.y, w0, w1);
            A4[2 * tid + 1] = make_float4(2*r1.z, 2*r2.y, 2*r1.w, 2*r2.z);
            Bq[2 * tid + 1] = make_float4(2*r2.x, 2*r2.w, w2, w3);
        }
        __syncthreads();

#pragma unroll 4
        for (int j = 0; j < 32; ++j) {             // pair (2k, 2k+1), k = j*16+sA
            const float4 a = A4[j * 16 + sA];      // -> ds_read_b128, imm offset
            const float4 bq = Bq[j * 16 + sA];
            const v2f sx = {a.x, a.y};
            const v2f sy = {a.z, a.w};
            const v2f sz = {bq.x, bq.y};
            const v2f sw = {bq.z, bq.w};
#pragma unroll
            for (int k = 0; k < 16; ++k) {
                const v2f t = fma2(splat(nx[k]), sx,
                              fma2(splat(ny[k]), sy,
                              fma2(splat(nz[k]), sz, sw)));
                best[k] = fminf(best[k], fminf(t.x, t.y));   // -> v_min3_f32
            }
        }

#pragma unroll
        for (int off = 1; off < 16; off <<= 1) {
#pragma unroll
            for (int k = 0; k < 16; ++k) best[k] = fminf(best[k], __shfl_xor(best[k], off));
        }
        if (sA == 0) {
#pragma unroll
            for (int k = 0; k < 16; ++k) {
                const float pp = fmaf(nx[k], nx[k], fmaf(ny[k], ny[k], nz[k] * nz[k]));
                v += sqrtf(fmaxf(best[k] + pp, EPS_));
            }
            v *= 1e-4f;
        }
    } else {
        // ================= role 1: knn (cd2 + normal loss) =================
        const int id  = blockIdx.x - 256;
        const int b   = id >> 5;                   // 32 blocks per b
        const int sub = id & 31;
        const int s   = tid & 31;
        const int g   = tid >> 5;                  // 0..7
        const int m0  = sub * 32 + g * 4;          // 4 chains per lane

        float m2x[4], m2y[4], m2z[4], aa[4];
        uint32_t k1[4], k2[4];
        {
            const float* sq = skel_xyz + ((size_t)b * M_ + m0) * 3;
#pragma unroll
            for (int c = 0; c < 4; ++c) {
                const float x = sq[c * 3 + 0];
                const float y = sq[c * 3 + 1];
                const float z = sq[c * 3 + 2];
                m2x[c] = -2.0f * x; m2y[c] = -2.0f * y; m2z[c] = -2.0f * z;
                aa[c]  = fmaf(x, x, fmaf(y, y, z * z));
                k1[c] = 0xFFFFFFFFu; k2[c] = 0xFFFFFFFFu;
            }
        }
        // wave-local positivity constant: C >= aa_c for every chain whose
        // keys this wave merges (merge is intra-wave). Constant per chain ->
        // ordering preserved; margin keeps t > 0 under fma rounding.
        float amax = fmaxf(fmaxf(aa[0], aa[1]), fmaxf(aa[2], aa[3]));
#pragma unroll
        for (int off = 1; off < 64; off <<= 1) amax = fmaxf(amax, __shfl_xor(amax, off));
        const float C = amax * 1.03125f;

        const uint32_t HI = 0xFFFFF000u;
        const float* sb = shape_xyz + (size_t)b * N_ * 6;
        const float4* g4 = (const float4*)sb;

        // prefetch phase 0: thread t holds float4 12t..12t+11 = pts 8t..8t+7
        float4 r[12];
#pragma unroll
        for (int k = 0; k < 12; ++k) r[k] = g4[12 * tid + k];

        for (int ph = 0; ph < 2; ++ph) {
            __syncthreads();                       // previous ls contents consumed
#pragma unroll
            for (int h = 0; h < 2; ++h) {          // pts 8t+4h..8t+4h+3 = pairs 4t+2h, 4t+2h+1
                const float4 a0 = r[6 * h + 0], a1 = r[6 * h + 1], a2 = r[6 * h + 2];
                const float4 a3 = r[6 * h + 3], a4 = r[6 * h + 4], a5 = r[6 * h + 5];
                // pts: q0=(a0.x,a0.y,a0.z) q1=(a1.z,a1.w,a2.x) q2=(a3.x,a3.y,a3.z) q3=(a4.z,a4.w,a5.x)
                const float w0 = fmaf(a0.x, a0.x, fmaf(a0.y, a0.y, a0.z * a0.z));
                const float w1 = fmaf(a1.z, a1.z, fmaf(a1.w, a1.w, a2.x * a2.x));
                const float w2 = fmaf(a3.x, a3.x, fmaf(a3.y, a3.y, a3.z * a3.z));
                const float w3 = fmaf(a4.z, a4.z, fmaf(a4.w, a4.w, a5.x * a5.x));
                A4[4 * tid + 2 * h + 0] = make_float4(a0.x, a1.z, a0.y, a1.w);
                Bq[4 * tid + 2 * h + 0] = make_float4(a0.z, a2.x, w0, w1);
                A4[4 * tid + 2 * h + 1] = make_float4(a3.x, a4.z, a3.y, a4.w);
                Bq[4 * tid + 2 * h + 1] = make_float4(a3.z, a5.x, w2, w3);
            }
            __syncthreads();
            // issue next phase's loads now; j-loop below hides their latency
            if (ph == 0) {
#pragma unroll
                for (int k = 0; k < 12; ++k) r[k] = g4[3072 + 12 * tid + k];
            }
            const uint32_t nb = (uint32_t)(ph * 2048);

#pragma unroll 4
            for (int j = 0; j < 32; ++j) {         // pair (2k, 2k+1), k = j*32+s
                const float4 a = A4[j * 32 + s];   // -> ds_read_b128, imm offset
                const float4 bq = Bq[j * 32 + s];
                const v2f qx = {a.x, a.y};
                const v2f qy = {a.z, a.w};
                const v2f qz = {bq.x, bq.y};
                const v2f qwc = (v2f){bq.z, bq.w} + splat(C);   // one pk_add, 4 chains
                const uint32_t gn0 = nb + (uint32_t)(j * 64 + 2 * s);
                const uint32_t gn1 = gn0 + 1u;
#pragma unroll
                for (int c = 0; c < 4; ++c) {
                    const v2f t = fma2(splat(m2x[c]), qx,
                                  fma2(splat(m2y[c]), qy,
                                  fma2(splat(m2z[c]), qz, qwc)));
                    const uint32_t kk0 = (__float_as_uint(t.x) & HI) | gn0;
                    const uint32_t kk1 = (__float_as_uint(t.y) & HI) | gn1;
                    k2[c] = min(k2[c], umed3(k1[c], kk0, kk1));
                    k1[c] = umin3(k1[c], kk0, kk1);
                }
            }
        }

        // butterfly top-2 merge across the 32 s-lanes
#pragma unroll
        for (int off = 1; off < 32; off <<= 1) {
#pragma unroll
            for (int c = 0; c < 4; ++c) {
                const uint32_t o1 = (uint32_t)__shfl_xor((int)k1[c], off);
                const uint32_t o2 = (uint32_t)__shfl_xor((int)k2[c], off);
                const uint32_t nk2 = min(min(k2[c], o2), max(k1[c], o1));
                k1[c] = min(k1[c], o1);
                k2[c] = nk2;
            }
        }

        if (s == 0) {
            const float* no = skel_nori + ((size_t)b * M_ + m0) * 3;
            const float kN = 0.001f * 0.5f / (float)B_;
#pragma unroll
            for (int c = 0; c < 4; ++c) {
                const int i1 = (int)(k1[c] & 0xFFFu);
                const int i2 = (int)(k2[c] & 0xFFFu);
                const float* p1 = sb + (size_t)i1 * 6;
                const float* p2 = sb + (size_t)i2 * 6;
                // exact nearest distance (removes key quantization from cd2)
                const float ax = -0.5f * m2x[c], ay = -0.5f * m2y[c], az = -0.5f * m2z[c];
                const float dx = ax - p1[0], dy = ay - p1[1], dz = az - p1[2];
                const float d2 = fmaf(dx, dx, fmaf(dy, dy, dz * dz));
                const float q0 = no[c * 3 + 0], q1 = no[c * 3 + 1], q2 = no[c * 3 + 2];
                const float dot1 = q0 * p1[3] + q1 * p1[4] + q2 * p1[5];
                const float dot2 = q0 * p2[3] + q1 * p2[4] + q2 * p2[5];
                v += sqrtf(fmaxf(d2, EPS_)) * 1e-4f + (fabsf(dot1) + fabsf(dot2)) * kN;
            }
        }
    }

    // wave reduction + one atomic per wave (no LDS -> block stays at 32768 B)
#pragma unroll
    for (int off = 32; off > 0; off >>= 1) v += __shfl_down(v, off);
    if ((tid & 63) == 0) atomicAdd(out, v);
}

extern "C" void kernel_launch(void* const* d_in, const int* in_sizes, int n_in,
                              void* d_out, int out_size, void* d_ws, size_t ws_size,
                              hipStream_t stream) {
    const float* shape_xyz = (const float*)d_in[0];  // (16, 4096, 6)
    const float* skel_xyz  = (const float*)d_in[1];  // (16, 1024, 3)
    const float* skel_nori = (const float*)d_in[2];  // (16, 1024, 3)
    float* out = (float*)d_out;                      // scalar

    hipMemsetAsync(out, 0, sizeof(float), stream);   // d_out poisoned each call
    fused_kernel<<<768, 256, 0, stream>>>(shape_xyz, skel_xyz, skel_nori, out);
}

// Round 18
// 84.231 us; speedup vs baseline: 2.8298x; 1.3357x over previous
//
#include <hip/hip_runtime.h>
#include <cfloat>
#include <stdint.h>

#define B_ 16
#define N_ 4096
#define M_ 1024
#define EPS_ 1e-12f

typedef float v2f __attribute__((ext_vector_type(2)));

__device__ __forceinline__ v2f fma2(v2f a, v2f b, v2f c) {
    return __builtin_elementwise_fma(a, b, c);     // -> v_pk_fma_f32
}
__device__ __forceinline__ v2f splat(float x) { return (v2f){x, x}; }

__device__ __forceinline__ uint32_t umin3(uint32_t a, uint32_t b, uint32_t c) {
    return min(a, min(b, c));                      // -> v_min3_u32
}
__device__ __forceinline__ uint32_t umed3(uint32_t a, uint32_t b, uint32_t c) {
    return max(min(a, b), min(max(a, b), c));      // -> v_med3_u32
}

// R17 structure (32768 B LDS -> 5 blocks/CU, wave-local C) with the R17
// regression fixed: final reduction is per-wave shfl -> partials in ls[0..3]
// (ls is dead after the hot loops; one barrier) -> ONE atomicAdd per block
// (768 total). R17's 4 per-wave atomics (3072, same address) serialized at
// L2 and became the critical path (57.8 us, VALUBusy 25%).
// 768 blocks. AoS-PAIR LDS: A[k]=(x2k,x2k+1,y2k,y2k+1), B[k]=(z..,w..);
// each j-iter = 2 ds_read_b128 with 16-bit imm offsets, zero addr VALU.
// blocks [0,256):  cd1, 256 pts each; sA=tid&15 owns pair k=j*16+sA,
//   gA=tid>>4 owns 16 pts. A doubled coords, B=(2z..,|s|^2..); per pt per
//   pair: 3 pk_fma + v_min3_f32 (|p|^2 added post-min; monotone).
// blocks [256,768): knn (cd2+normal), 32 m each; s=tid&31 owns pair
//   k=j*32+s, g=tid>>5 owns 4 chains. 2 staging phases of 2048 pts.
//   Key t = d^2 + (C - aa_c) >= 0 (C = wave-max |m|^2 * 1.03125, constant
//   per chain -> ordering preserved; t >= 0 so uint key order == float
//   order). Packed key = (bits(t)&~0xFFF)|n (low 12 bits break ties toward
//   smaller n like top_k). Exact distance recomputed for winners.
__global__ __launch_bounds__(256, 3) void fused_kernel(const float* __restrict__ shape_xyz,
                                                       const float* __restrict__ skel_xyz,
                                                       const float* __restrict__ skel_nori,
                                                       float* __restrict__ out)
{
    __shared__ float ls[8192];     // exactly 32 KB: A = ls[0..4095], B = ls[4096..8191]

    const int tid = threadIdx.x;
    float4* A4 = (float4*)ls;
    float4* Bq = (float4*)(ls + 4096);
    float v = 0.0f;

    if (blockIdx.x < 256) {
        // ================= role 0: cd1 =================
        const int b    = blockIdx.x >> 4;      // 16 tiles per b
        const int tile = blockIdx.x & 15;

        // skel staging: thread t loads float4 3t..3t+2 = pts 4t..4t+3 = pairs 2t,2t+1
        const float4* g4 = (const float4*)(skel_xyz + (size_t)b * M_ * 3);
        const float4 r0 = g4[3 * tid + 0];
        const float4 r1 = g4[3 * tid + 1];
        const float4 r2 = g4[3 * tid + 2];

        const int sA = tid & 15;
        const int gA = tid >> 4;
        const int n0 = tile * 256 + gA * 16;
        const float* p = shape_xyz + ((size_t)b * N_ + n0) * 6;
        float nx[16], ny[16], nz[16], best[16];
#pragma unroll
        for (int k = 0; k < 16; ++k) {
            nx[k] = -p[k * 6 + 0];
            ny[k] = -p[k * 6 + 1];
            nz[k] = -p[k * 6 + 2];
            best[k] = FLT_MAX;
        }

        {
            // pts: p0=(r0.x,r0.y,r0.z) p1=(r0.w,r1.x,r1.y) p2=(r1.z,r1.w,r2.x) p3=(r2.y,r2.z,r2.w)
            const float w0 = fmaf(r0.x, r0.x, fmaf(r0.y, r0.y, r0.z * r0.z));
            const float w1 = fmaf(r0.w, r0.w, fmaf(r1.x, r1.x, r1.y * r1.y));
            const float w2 = fmaf(r1.z, r1.z, fmaf(r1.w, r1.w, r2.x * r2.x));
            const float w3 = fmaf(r2.y, r2.y, fmaf(r2.z, r2.z, r2.w * r2.w));
            A4[2 * tid + 0] = make_float4(2*r0.x, 2*r0.w, 2*r0.y, 2*r1.x);
            Bq[2 * tid + 0] = make_float4(2*r0.z, 2*r1.y, w0, w1);
            A4[2 * tid + 1] = make_float4(2*r1.z, 2*r2.y, 2*r1.w, 2*r2.z);
            Bq[2 * tid + 1] = make_float4(2*r2.x, 2*r2.w, w2, w3);
        }
        __syncthreads();

#pragma unroll 4
        for (int j = 0; j < 32; ++j) {             // pair (2k, 2k+1), k = j*16+sA
            const float4 a = A4[j * 16 + sA];      // -> ds_read_b128, imm offset
            const float4 bq = Bq[j * 16 + sA];
            const v2f sx = {a.x, a.y};
            const v2f sy = {a.z, a.w};
            const v2f sz = {bq.x, bq.y};
            const v2f sw = {bq.z, bq.w};
#pragma unroll
            for (int k = 0; k < 16; ++k) {
                const v2f t = fma2(splat(nx[k]), sx,
                              fma2(splat(ny[k]), sy,
                              fma2(splat(nz[k]), sz, sw)));
                best[k] = fminf(best[k], fminf(t.x, t.y));   // -> v_min3_f32
            }
        }

#pragma unroll
        for (int off = 1; off < 16; off <<= 1) {
#pragma unroll
            for (int k = 0; k < 16; ++k) best[k] = fminf(best[k], __shfl_xor(best[k], off));
        }
        if (sA == 0) {
#pragma unroll
            for (int k = 0; k < 16; ++k) {
                const float pp = fmaf(nx[k], nx[k], fmaf(ny[k], ny[k], nz[k] * nz[k]));
                v += sqrtf(fmaxf(best[k] + pp, EPS_));
            }
            v *= 1e-4f;
        }
    } else {
        // ================= role 1: knn (cd2 + normal loss) =================
        const int id  = blockIdx.x - 256;
        const int b   = id >> 5;                   // 32 blocks per b
        const int sub = id & 31;
        const int s   = tid & 31;
        const int g   = tid >> 5;                  // 0..7
        const int m0  = sub * 32 + g * 4;          // 4 chains per lane

        float m2x[4], m2y[4], m2z[4], aa[4];
        uint32_t k1[4], k2[4];
        {
            const float* sq = skel_xyz + ((size_t)b * M_ + m0) * 3;
#pragma unroll
            for (int c = 0; c < 4; ++c) {
                const float x = sq[c * 3 + 0];
                const float y = sq[c * 3 + 1];
                const float z = sq[c * 3 + 2];
                m2x[c] = -2.0f * x; m2y[c] = -2.0f * y; m2z[c] = -2.0f * z;
                aa[c]  = fmaf(x, x, fmaf(y, y, z * z));
                k1[c] = 0xFFFFFFFFu; k2[c] = 0xFFFFFFFFu;
            }
        }
        // wave-local positivity constant: C >= aa_c for every chain whose
        // keys this wave merges (merge is intra-wave). Constant per chain ->
        // ordering preserved; margin keeps t > 0 under fma rounding.
        float amax = fmaxf(fmaxf(aa[0], aa[1]), fmaxf(aa[2], aa[3]));
#pragma unroll
        for (int off = 1; off < 64; off <<= 1) amax = fmaxf(amax, __shfl_xor(amax, off));
        const float C = amax * 1.03125f;

        const uint32_t HI = 0xFFFFF000u;
        const float* sb = shape_xyz + (size_t)b * N_ * 6;
        const float4* g4 = (const float4*)sb;

        // prefetch phase 0: thread t holds float4 12t..12t+11 = pts 8t..8t+7
        float4 r[12];
#pragma unroll
        for (int k = 0; k < 12; ++k) r[k] = g4[12 * tid + k];

        for (int ph = 0; ph < 2; ++ph) {
            __syncthreads();                       // previous ls contents consumed
#pragma unroll
            for (int h = 0; h < 2; ++h) {          // pts 8t+4h..8t+4h+3 = pairs 4t+2h, 4t+2h+1
                const float4 a0 = r[6 * h + 0], a1 = r[6 * h + 1], a2 = r[6 * h + 2];
                const float4 a3 = r[6 * h + 3], a4 = r[6 * h + 4], a5 = r[6 * h + 5];
                // pts: q0=(a0.x,a0.y,a0.z) q1=(a1.z,a1.w,a2.x) q2=(a3.x,a3.y,a3.z) q3=(a4.z,a4.w,a5.x)
                const float w0 = fmaf(a0.x, a0.x, fmaf(a0.y, a0.y, a0.z * a0.z));
                const float w1 = fmaf(a1.z, a1.z, fmaf(a1.w, a1.w, a2.x * a2.x));
                const float w2 = fmaf(a3.x, a3.x, fmaf(a3.y, a3.y, a3.z * a3.z));
                const float w3 = fmaf(a4.z, a4.z, fmaf(a4.w, a4.w, a5.x * a5.x));
                A4[4 * tid + 2 * h + 0] = make_float4(a0.x, a1.z, a0.y, a1.w);
                Bq[4 * tid + 2 * h + 0] = make_float4(a0.z, a2.x, w0, w1);
                A4[4 * tid + 2 * h + 1] = make_float4(a3.x, a4.z, a3.y, a4.w);
                Bq[4 * tid + 2 * h + 1] = make_float4(a3.z, a5.x, w2, w3);
            }
            __syncthreads();
            // issue next phase's loads now; j-loop below hides their latency
            if (ph == 0) {
#pragma unroll
                for (int k = 0; k < 12; ++k) r[k] = g4[3072 + 12 * tid + k];
            }
            const uint32_t nb = (uint32_t)(ph * 2048);

#pragma unroll 4
            for (int j = 0; j < 32; ++j) {         // pair (2k, 2k+1), k = j*32+s
                const float4 a = A4[j * 32 + s];   // -> ds_read_b128, imm offset
                const float4 bq = Bq[j * 32 + s];
                const v2f qx = {a.x, a.y};
                const v2f qy = {a.z, a.w};
                const v2f qz = {bq.x, bq.y};
                const v2f qwc = (v2f){bq.z, bq.w} + splat(C);   // one pk_add, 4 chains
                const uint32_t gn0 = nb + (uint32_t)(j * 64 + 2 * s);
                const uint32_t gn1 = gn0 + 1u;
#pragma unroll
                for (int c = 0; c < 4; ++c) {
                    const v2f t = fma2(splat(m2x[c]), qx,
                                  fma2(splat(m2y[c]), qy,
                                  fma2(splat(m2z[c]), qz, qwc)));
                    const uint32_t kk0 = (__float_as_uint(t.x) & HI) | gn0;
                    const uint32_t kk1 = (__float_as_uint(t.y) & HI) | gn1;
                    k2[c] = min(k2[c], umed3(k1[c], kk0, kk1));
                    k1[c] = umin3(k1[c], kk0, kk1);
                }
            }
        }

        // butterfly top-2 merge across the 32 s-lanes
#pragma unroll
        for (int off = 1; off < 32; off <<= 1) {
#pragma unroll
            for (int c = 0; c < 4; ++c) {
                const uint32_t o1 = (uint32_t)__shfl_xor((int)k1[c], off);
                const uint32_t o2 = (uint32_t)__shfl_xor((int)k2[c], off);
                const uint32_t nk2 = min(min(k2[c], o2), max(k1[c], o1));
                k1[c] = min(k1[c], o1);
                k2[c] = nk2;
            }
        }

        if (s == 0) {
            const float* no = skel_nori + ((size_t)b * M_ + m0) * 3;
            const float kN = 0.001f * 0.5f / (float)B_;
#pragma unroll
            for (int c = 0; c < 4; ++c) {
                const int i1 = (int)(k1[c] & 0xFFFu);
                const int i2 = (int)(k2[c] & 0xFFFu);
                const float* p1 = sb + (size_t)i1 * 6;
                const float* p2 = sb + (size_t)i2 * 6;
                // exact nearest distance (removes key quantization from cd2)
                const float ax = -0.5f * m2x[c], ay = -0.5f * m2y[c], az = -0.5f * m2z[c];
                const float dx = ax - p1[0], dy = ay - p1[1], dz = az - p1[2];
                const float d2 = fmaf(dx, dx, fmaf(dy, dy, dz * dz));
                const float q0 = no[c * 3 + 0], q1 = no[c * 3 + 1], q2 = no[c * 3 + 2];
                const float dot1 = q0 * p1[3] + q1 * p1[4] + q2 * p1[5];
                const float dot2 = q0 * p2[3] + q1 * p2[4] + q2 * p2[5];
                v += sqrtf(fmaxf(d2, EPS_)) * 1e-4f + (fabsf(dot1) + fabsf(dot2)) * kN;
            }
        }
    }

    // block reduction reusing ls (dead after hot loops) -> ONE atomic/block
#pragma unroll
    for (int off = 32; off > 0; off >>= 1) v += __shfl_down(v, off);
    __syncthreads();                     // all hot-loop ls reads complete
    if ((tid & 63) == 0) ls[tid >> 6] = v;
    __syncthreads();
    if (tid == 0) atomicAdd(out, ls[0] + ls[1] + ls[2] + ls[3]);
}

extern "C" void kernel_launch(void* const* d_in, const int* in_sizes, int n_in,
                              void* d_out, int out_size, void* d_ws, size_t ws_size,
                              hipStream_t stream) {
    const float* shape_xyz = (const float*)d_in[0];  // (16, 4096, 6)
    const float* skel_xyz  = (const float*)d_in[1];  // (16, 1024, 3)
    const float* skel_nori = (const float*)d_in[2];  // (16, 1024, 3)
    float* out = (float*)d_out;                      // scalar

    hipMemsetAsync(out, 0, sizeof(float), stream);   // d_out poisoned each call
    fused_kernel<<<768, 256, 0, stream>>>(shape_xyz, skel_xyz, skel_nori, out);
}

// Round 19
// 81.645 us; speedup vs baseline: 2.9194x; 1.0317x over previous
//
#include <hip/hip_runtime.h>
#include <cfloat>
#include <stdint.h>

#define B_ 16
#define N_ 4096
#define M_ 1024
#define EPS_ 1e-12f

typedef float v2f __attribute__((ext_vector_type(2)));

__device__ __forceinline__ v2f fma2(v2f a, v2f b, v2f c) {
    return __builtin_elementwise_fma(a, b, c);     // -> v_pk_fma_f32
}
__device__ __forceinline__ v2f splat(float x) { return (v2f){x, x}; }

__device__ __forceinline__ uint32_t umin3(uint32_t a, uint32_t b, uint32_t c) {
    return min(a, min(b, c));                      // -> v_min3_u32
}
__device__ __forceinline__ uint32_t umed3(uint32_t a, uint32_t b, uint32_t c) {
    return max(min(a, b), min(max(a, b), c));      // -> v_med3_u32
}

// FINAL: exact revert to R14 — the session's empirical best (82.6 us).
// 768 blocks = 3/CU (grid-limited; LDS-capacity pushes R16-R18 showed no
// gain is available without more blocks, and all cheap block-multiplying
// schemes regress: staging duplication / spills / atomic serialization).
// AoS-PAIR LDS layout: pair = two ADJACENT points (n,n+1):
// A[k]=(x2k,x2k+1,y2k,y2k+1), B[k]=(z2k,z2k+1,w2k,w2k+1); each j-iter =
// 2 ds_read_b128 with 16-bit imm offsets, zero per-iter addr VALU; packed
// fp32 (v_pk_fma_f32) cores.
// blocks [0,256):  cd1, 256 pts each; sA=tid&15 owns pair k=j*16+sA,
//   gA=tid>>4 owns 16 pts. A doubled coords, B=(2z..,|s|^2..); per pt per
//   pair: 3 pk_fma + v_min3_f32 (|p|^2 added post-min; monotone).
// blocks [256,768): knn (cd2+normal), 32 m each; s=tid&31 owns pair
//   k=j*32+s, g=tid>>5 owns 4 chains. 2 staging phases of 2048 pts (32 KB).
//   B.w = |q|^2 + C_block at staging (C_block = block-max |m|^2, uniform
//   across merge lanes and per chain -> ordering preserved, t >= 0 so uint
//   key order == float order). Packed key = (bits(t)&~0xFFF)|n (low 12 bits
//   break ties toward smaller n like top_k). Exact distance recomputed for
//   winners in the epilogue.
__global__ __launch_bounds__(256, 3) void fused_kernel(const float* __restrict__ shape_xyz,
                                                       const float* __restrict__ skel_xyz,
                                                       const float* __restrict__ skel_nori,
                                                       float* __restrict__ out)
{
    __shared__ float ls[8192];     // 32 KB: A = ls[0..4095], B = ls[4096..8191]
    __shared__ float ws[4];

    const int tid = threadIdx.x;
    float4* A4 = (float4*)ls;
    float4* Bq = (float4*)(ls + 4096);
    float v = 0.0f;

    if (blockIdx.x < 256) {
        // ================= role 0: cd1 =================
        const int b    = blockIdx.x >> 4;      // 16 tiles per b
        const int tile = blockIdx.x & 15;

        // skel staging: thread t loads float4 3t..3t+2 = pts 4t..4t+3 = pairs 2t,2t+1
        const float4* g4 = (const float4*)(skel_xyz + (size_t)b * M_ * 3);
        const float4 r0 = g4[3 * tid + 0];
        const float4 r1 = g4[3 * tid + 1];
        const float4 r2 = g4[3 * tid + 2];

        const int sA = tid & 15;
        const int gA = tid >> 4;
        const int n0 = tile * 256 + gA * 16;
        const float* p = shape_xyz + ((size_t)b * N_ + n0) * 6;
        float nx[16], ny[16], nz[16], best[16];
#pragma unroll
        for (int k = 0; k < 16; ++k) {
            nx[k] = -p[k * 6 + 0];
            ny[k] = -p[k * 6 + 1];
            nz[k] = -p[k * 6 + 2];
            best[k] = FLT_MAX;
        }

        {
            // pts: p0=(r0.x,r0.y,r0.z) p1=(r0.w,r1.x,r1.y) p2=(r1.z,r1.w,r2.x) p3=(r2.y,r2.z,r2.w)
            const float w0 = fmaf(r0.x, r0.x, fmaf(r0.y, r0.y, r0.z * r0.z));
            const float w1 = fmaf(r0.w, r0.w, fmaf(r1.x, r1.x, r1.y * r1.y));
            const float w2 = fmaf(r1.z, r1.z, fmaf(r1.w, r1.w, r2.x * r2.x));
            const float w3 = fmaf(r2.y, r2.y, fmaf(r2.z, r2.z, r2.w * r2.w));
            A4[2 * tid + 0] = make_float4(2*r0.x, 2*r0.w, 2*r0.y, 2*r1.x);
            Bq[2 * tid + 0] = make_float4(2*r0.z, 2*r1.y, w0, w1);
            A4[2 * tid + 1] = make_float4(2*r1.z, 2*r2.y, 2*r1.w, 2*r2.z);
            Bq[2 * tid + 1] = make_float4(2*r2.x, 2*r2.w, w2, w3);
        }
        __syncthreads();

#pragma unroll 4
        for (int j = 0; j < 32; ++j) {             // pair (2k, 2k+1), k = j*16+sA
            const float4 a = A4[j * 16 + sA];      // -> ds_read_b128, imm offset
            const float4 bq = Bq[j * 16 + sA];
            const v2f sx = {a.x, a.y};
            const v2f sy = {a.z, a.w};
            const v2f sz = {bq.x, bq.y};
            const v2f sw = {bq.z, bq.w};
#pragma unroll
            for (int k = 0; k < 16; ++k) {
                const v2f t = fma2(splat(nx[k]), sx,
                              fma2(splat(ny[k]), sy,
                              fma2(splat(nz[k]), sz, sw)));
                best[k] = fminf(best[k], fminf(t.x, t.y));   // -> v_min3_f32
            }
        }

#pragma unroll
        for (int off = 1; off < 16; off <<= 1) {
#pragma unroll
            for (int k = 0; k < 16; ++k) best[k] = fminf(best[k], __shfl_xor(best[k], off));
        }
        if (sA == 0) {
#pragma unroll
            for (int k = 0; k < 16; ++k) {
                const float pp = fmaf(nx[k], nx[k], fmaf(ny[k], ny[k], nz[k] * nz[k]));
                v += sqrtf(fmaxf(best[k] + pp, EPS_));
            }
            v *= 1e-4f;
        }
    } else {
        // ================= role 1: knn (cd2 + normal loss) =================
        const int id  = blockIdx.x - 256;
        const int b   = id >> 5;                   // 32 blocks per b
        const int sub = id & 31;
        const int s   = tid & 31;
        const int g   = tid >> 5;                  // 0..7
        const int m0  = sub * 32 + g * 4;          // 4 chains per lane

        float m2x[4], m2y[4], m2z[4], aa[4];
        uint32_t k1[4], k2[4];
        {
            const float* sq = skel_xyz + ((size_t)b * M_ + m0) * 3;
#pragma unroll
            for (int c = 0; c < 4; ++c) {
                const float x = sq[c * 3 + 0];
                const float y = sq[c * 3 + 1];
                const float z = sq[c * 3 + 2];
                m2x[c] = -2.0f * x; m2y[c] = -2.0f * y; m2z[c] = -2.0f * z;
                aa[c]  = fmaf(x, x, fmaf(y, y, z * z));
                k1[c] = 0xFFFFFFFFu; k2[c] = 0xFFFFFFFFu;
            }
        }
        // block-max of aa -> C (uniform across merge lanes; per chain the key
        // value is d^2 + (C - aa_c), a constant shift -> ordering preserved)
        float amax = fmaxf(fmaxf(aa[0], aa[1]), fmaxf(aa[2], aa[3]));
#pragma unroll
        for (int off = 1; off < 64; off <<= 1) amax = fmaxf(amax, __shfl_xor(amax, off));
        if ((tid & 63) == 0) ws[tid >> 6] = amax;

        const uint32_t HI = 0xFFFFF000u;
        const float* sb = shape_xyz + (size_t)b * N_ * 6;
        const float4* g4 = (const float4*)sb;

        // prefetch phase 0: thread t holds float4 12t..12t+11 = pts 8t..8t+7
        float4 r[12];
#pragma unroll
        for (int k = 0; k < 12; ++k) r[k] = g4[12 * tid + k];

        float C = 0.0f;
        for (int ph = 0; ph < 2; ++ph) {
            __syncthreads();   // ph0: ws visible; ph1: previous ls reads done
            if (ph == 0) C = fmaxf(fmaxf(ws[0], ws[1]), fmaxf(ws[2], ws[3]));
#pragma unroll
            for (int h = 0; h < 2; ++h) {          // pts 8t+4h..8t+4h+3 = pairs 4t+2h, 4t+2h+1
                const float4 a0 = r[6 * h + 0], a1 = r[6 * h + 1], a2 = r[6 * h + 2];
                const float4 a3 = r[6 * h + 3], a4 = r[6 * h + 4], a5 = r[6 * h + 5];
                // pts: q0=(a0.x,a0.y,a0.z) q1=(a1.z,a1.w,a2.x) q2=(a3.x,a3.y,a3.z) q3=(a4.z,a4.w,a5.x)
                const float w0 = fmaf(a0.x, a0.x, fmaf(a0.y, a0.y, a0.z * a0.z)) + C;
                const float w1 = fmaf(a1.z, a1.z, fmaf(a1.w, a1.w, a2.x * a2.x)) + C;
                const float w2 = fmaf(a3.x, a3.x, fmaf(a3.y, a3.y, a3.z * a3.z)) + C;
                const float w3 = fmaf(a4.z, a4.z, fmaf(a4.w, a4.w, a5.x * a5.x)) + C;
                A4[4 * tid + 2 * h + 0] = make_float4(a0.x, a1.z, a0.y, a1.w);
                Bq[4 * tid + 2 * h + 0] = make_float4(a0.z, a2.x, w0, w1);
                A4[4 * tid + 2 * h + 1] = make_float4(a3.x, a4.z, a3.y, a4.w);
                Bq[4 * tid + 2 * h + 1] = make_float4(a3.z, a5.x, w2, w3);
            }
            __syncthreads();
            // issue next phase's loads now; j-loop below hides their latency
            if (ph == 0) {
#pragma unroll
                for (int k = 0; k < 12; ++k) r[k] = g4[3072 + 12 * tid + k];
            }
            const uint32_t nb = (uint32_t)(ph * 2048);

#pragma unroll 4
            for (int j = 0; j < 32; ++j) {         // pair (2k, 2k+1), k = j*32+s
                const float4 a = A4[j * 32 + s];   // -> ds_read_b128, imm offset
                const float4 bq = Bq[j * 32 + s];
                const v2f qx = {a.x, a.y};
                const v2f qy = {a.z, a.w};
                const v2f qz = {bq.x, bq.y};
                const v2f qw = {bq.z, bq.w};
                const uint32_t gn0 = nb + (uint32_t)(j * 64 + 2 * s);
                const uint32_t gn1 = gn0 + 1u;
#pragma unroll
                for (int c = 0; c < 4; ++c) {
                    const v2f t = fma2(splat(m2x[c]), qx,
                                  fma2(splat(m2y[c]), qy,
                                  fma2(splat(m2z[c]), qz, qw)));
                    const uint32_t kk0 = (__float_as_uint(t.x) & HI) | gn0;
                    const uint32_t kk1 = (__float_as_uint(t.y) & HI) | gn1;
                    k2[c] = min(k2[c], umed3(k1[c], kk0, kk1));
                    k1[c] = umin3(k1[c], kk0, kk1);
                }
            }
        }

        // butterfly top-2 merge across the 32 s-lanes
#pragma unroll
        for (int off = 1; off < 32; off <<= 1) {
#pragma unroll
            for (int c = 0; c < 4; ++c) {
                const uint32_t o1 = (uint32_t)__shfl_xor((int)k1[c], off);
                const uint32_t o2 = (uint32_t)__shfl_xor((int)k2[c], off);
                const uint32_t nk2 = min(min(k2[c], o2), max(k1[c], o1));
                k1[c] = min(k1[c], o1);
                k2[c] = nk2;
            }
        }

        if (s == 0) {
            const float* no = skel_nori + ((size_t)b * M_ + m0) * 3;
            const float kN = 0.001f * 0.5f / (float)B_;
#pragma unroll
            for (int c = 0; c < 4; ++c) {
                const int i1 = (int)(k1[c] & 0xFFFu);
                const int i2 = (int)(k2[c] & 0xFFFu);
                const float* p1 = sb + (size_t)i1 * 6;
                const float* p2 = sb + (size_t)i2 * 6;
                // exact nearest distance (removes key quantization from cd2)
                const float ax = -0.5f * m2x[c], ay = -0.5f * m2y[c], az = -0.5f * m2z[c];
                const float dx = ax - p1[0], dy = ay - p1[1], dz = az - p1[2];
                const float d2 = fmaf(dx, dx, fmaf(dy, dy, dz * dz));
                const float q0 = no[c * 3 + 0], q1 = no[c * 3 + 1], q2 = no[c * 3 + 2];
                const float dot1 = q0 * p1[3] + q1 * p1[4] + q2 * p1[5];
                const float dot2 = q0 * p2[3] + q1 * p2[4] + q2 * p2[5];
                v += sqrtf(fmaxf(d2, EPS_)) * 1e-4f + (fabsf(dot1) + fabsf(dot2)) * kN;
            }
        }
    }

    // block reduction + one atomic per block
#pragma unroll
    for (int off = 32; off > 0; off >>= 1) v += __shfl_down(v, off);
    __syncthreads();                     // ws safely reusable (role 1 read it in ph0)
    if ((tid & 63) == 0) ws[tid >> 6] = v;
    __syncthreads();
    if (tid == 0) atomicAdd(out, ws[0] + ws[1] + ws[2] + ws[3]);
}

extern "C" void kernel_launch(void* const* d_in, const int* in_sizes, int n_in,
                              void* d_out, int out_size, void* d_ws, size_t ws_size,
                              hipStream_t stream) {
    const float* shape_xyz = (const float*)d_in[0];  // (16, 4096, 6)
    const float* skel_xyz  = (const float*)d_in[1];  // (16, 1024, 3)
    const float* skel_nori = (const float*)d_in[2];  // (16, 1024, 3)
    float* out = (float*)d_out;                      // scalar

    hipMemsetAsync(out, 0, sizeof(float), stream);   // d_out poisoned each call
    fused_kernel<<<768, 256, 0, stream>>>(shape_xyz, skel_xyz, skel_nori, out);
}